// Round 1
// baseline (614.515 us; speedup 1.0000x reference)
//
#include <hip/hip_runtime.h>
#include <hip/hip_bf16.h>
#include <stdint.h>

#define B_ 2
#define T_ 2048
#define C_ 2048
#define H_ 16
#define HKV_ 4
#define D_ 128
#define M_ (B_*T_)          // 4096 rows of hidden_states
// scale * log2(e): exp(x*scale) == exp2(x * SCL)
static constexpr float SCL = 0.08838834764831845f * 1.4426950408889634f;
static constexpr float EPS_ = 1e-6f;

typedef short bf16x8 __attribute__((ext_vector_type(8)));
typedef float f32x4 __attribute__((ext_vector_type(4)));

__device__ __forceinline__ f32x4 zero4() {
  f32x4 v; v[0] = 0.f; v[1] = 0.f; v[2] = 0.f; v[3] = 0.f; return v;
}

__device__ __forceinline__ unsigned short f2bf(float x) {
  union { float f; unsigned u; } v; v.f = x;
  unsigned r = (v.u + 0x7FFFu + ((v.u >> 16) & 1u)) >> 16;
  return (unsigned short)r;
}

__device__ __forceinline__ void gl_lds16(const void* g, void* l) {
  __builtin_amdgcn_global_load_lds((const __attribute__((address_space(1))) void*)g,
                                   (__attribute__((address_space(3))) void*)l, 16, 0, 0);
}

// ---------------- f32 -> bf16 elementwise convert ----------------
__global__ void k_cvt(const float* __restrict__ in, unsigned short* __restrict__ out, int n) {
  int i = (blockIdx.x * blockDim.x + threadIdx.x) * 8;
  int stride = gridDim.x * blockDim.x * 8;
  for (; i < n; i += stride) {
    float4 a = *(const float4*)(in + i);
    float4 b = *(const float4*)(in + i + 4);
    ushort4 o0; o0.x = f2bf(a.x); o0.y = f2bf(a.y); o0.z = f2bf(a.z); o0.w = f2bf(a.w);
    ushort4 o1; o1.x = f2bf(b.x); o1.y = f2bf(b.y); o1.z = f2bf(b.z); o1.w = f2bf(b.w);
    *(ushort4*)(out + i) = o0;
    *(ushort4*)(out + i + 4) = o1;
  }
}

// ------------- f32 -> bf16 transpose convert: out[c][r] = in[r][c] -------------
__global__ void k_cvt_t(const float* __restrict__ in, unsigned short* __restrict__ out,
                        int R, int Cc) {
  __shared__ float ld[32][33];
  int c0 = blockIdx.x * 32, r0 = blockIdx.y * 32;
  int x = threadIdx.x, y = threadIdx.y; // 32 x 8
#pragma unroll
  for (int i = 0; i < 4; i++)
    ld[y * 4 + i][x] = in[(size_t)(r0 + y * 4 + i) * Cc + c0 + x];
  __syncthreads();
#pragma unroll
  for (int i = 0; i < 4; i++)
    out[(size_t)(c0 + y * 4 + i) * R + r0 + x] = f2bf(ld[x][y * 4 + i]);
}

// ---------------- bf16 GEMM: C[M][N] = A[M][K] * Bt[N][K]^T ----------------
// BM=BN=128, BK=64, 256 threads (4 waves, 2x2), wave tile 64x64 (4x4 of 16x16)
template <int WRITE_F32>
__global__ __launch_bounds__(256) void k_gemm(const unsigned short* __restrict__ A,
                                              const unsigned short* __restrict__ Bt,
                                              void* __restrict__ Cout,
                                              int Mdim, int Ndim, int K) {
  __shared__ unsigned short As[128 * 64];
  __shared__ unsigned short Bs[128 * 64];
  const int tid = threadIdx.x;
  const int wid = tid >> 6, lane = tid & 63;
  const int wm = wid >> 1, wn = wid & 1;
  const int m0 = blockIdx.y * 128, n0 = blockIdx.x * 128;
  const int lrow = tid >> 3, lcol = (tid & 7) * 8;
  const int g = lane >> 4, lr = lane & 15;

  f32x4 acc[4][4];
#pragma unroll
  for (int i = 0; i < 4; i++)
#pragma unroll
    for (int j = 0; j < 4; j++) acc[i][j] = zero4();

  for (int k0 = 0; k0 < K; k0 += 64) {
    __syncthreads();
#pragma unroll
    for (int it = 0; it < 4; it++) {
      gl_lds16(A + (size_t)(m0 + lrow + it * 32) * K + k0 + lcol, (void*)(As + tid * 8 + it * 2048));
      gl_lds16(Bt + (size_t)(n0 + lrow + it * 32) * K + k0 + lcol, (void*)(Bs + tid * 8 + it * 2048));
    }
    __syncthreads();
#pragma unroll
    for (int kk = 0; kk < 2; kk++) {
      bf16x8 af[4], bfr[4];
#pragma unroll
      for (int i = 0; i < 4; i++)
        af[i] = *(const bf16x8*)(As + (wm * 64 + i * 16 + lr) * 64 + kk * 32 + g * 8);
#pragma unroll
      for (int j = 0; j < 4; j++)
        bfr[j] = *(const bf16x8*)(Bs + (wn * 64 + j * 16 + lr) * 64 + kk * 32 + g * 8);
#pragma unroll
      for (int i = 0; i < 4; i++)
#pragma unroll
        for (int j = 0; j < 4; j++)
          acc[i][j] = __builtin_amdgcn_mfma_f32_16x16x32_bf16(af[i], bfr[j], acc[i][j], 0, 0, 0);
    }
  }

#pragma unroll
  for (int i = 0; i < 4; i++)
#pragma unroll
    for (int j = 0; j < 4; j++)
#pragma unroll
      for (int r = 0; r < 4; r++) {
        int row = m0 + wm * 64 + i * 16 + g * 4 + r;
        int col = n0 + wn * 64 + j * 16 + lr;
        if (WRITE_F32)
          ((float*)Cout)[(size_t)row * Ndim + col] = acc[i][j][r];
        else
          ((unsigned short*)Cout)[(size_t)row * Ndim + col] = f2bf(acc[i][j][r]);
      }
}

// ---------------- fused causal GQA attention with prune+renorm ----------------
// grid (32 qtiles, 32 b*h), 256 threads = 4 waves; wave w owns q-rows qbase+w*16..+15
__global__ __launch_bounds__(256) void k_attn(const unsigned short* __restrict__ qb,  // [4096][2048]
                                              const unsigned short* __restrict__ kb,  // [4096][512]
                                              const unsigned short* __restrict__ vt,  // [512][4096]
                                              const int* __restrict__ mask,           // [2048]
                                              float* __restrict__ attn,               // [B,H,T,S]
                                              unsigned short* __restrict__ ctx)       // [4096][2048]
{
  __shared__ unsigned short Ks[64 * 128];
  __shared__ unsigned short Vs[128 * 64];
  __shared__ unsigned short Ps[4][16 * 64];
  __shared__ float keeps[2048];

  const int tid = threadIdx.x;
  const int wid = tid >> 6, lane = tid & 63;
  const int g = lane >> 4, lr = lane & 15;
  const int qt = blockIdx.x;
  const int bh = blockIdx.y;
  const int b = bh >> 4, h = bh & 15, hkv = h >> 2;
  const int qbase = qt * 64;

  const unsigned short* qp = qb + (size_t)(b * T_ + qbase) * 2048 + h * 128;
  const unsigned short* kp = kb + (size_t)(b * T_) * 512 + hkv * 128;
  const unsigned short* vp = vt + (size_t)(hkv * 128) * 4096 + b * T_;
  float* ap = attn + (size_t)(bh * T_ + qbase) * 2048;
  unsigned short* cp = ctx + (size_t)(b * T_ + qbase) * 2048 + h * 128;

#pragma unroll
  for (int i = 0; i < 8; i++)
    keeps[tid * 8 + i] = (mask[tid * 8 + i] != 0) ? 1.0f : 0.0f;

  // Q fragments (held in registers for both passes)
  bf16x8 qa[4];
#pragma unroll
  for (int ks = 0; ks < 4; ks++)
    qa[ks] = *(const bf16x8*)(qp + (size_t)(wid * 16 + lr) * 2048 + ks * 32 + g * 8);

  const int ntile = qt + 1;
  float z[4] = {0, 0, 0, 0}, zk[4] = {0, 0, 0, 0};

  const int srow = tid >> 4, scol = (tid & 15) * 8; // K staging: 16 thr/row of 128
  const int vrow = tid >> 3, vcol = (tid & 7) * 8;  // V staging: 8 thr/row of 64

  // ---- pass 1: row sums Z (all causal) and S_keep (kept causal) ----
  for (int st = 0; st < ntile; st++) {
    int s0 = st * 64;
    __syncthreads();
#pragma unroll
    for (int it = 0; it < 4; it++)
      gl_lds16(kp + (size_t)(s0 + srow + it * 16) * 512 + scol, (void*)(Ks + tid * 8 + it * 2048));
    __syncthreads();
#pragma unroll
    for (int j = 0; j < 4; j++) {
      f32x4 sc = zero4();
#pragma unroll
      for (int ks = 0; ks < 4; ks++) {
        bf16x8 kf = *(const bf16x8*)(Ks + (j * 16 + lr) * 128 + ks * 32 + g * 8);
        sc = __builtin_amdgcn_mfma_f32_16x16x32_bf16(qa[ks], kf, sc, 0, 0, 0);
      }
      int sg = s0 + j * 16 + lr;
      float kpv = keeps[sg];
#pragma unroll
      for (int r = 0; r < 4; r++) {
        int tg = qbase + wid * 16 + g * 4 + r;
        float e = (sg <= tg) ? __builtin_amdgcn_exp2f(sc[r] * SCL) : 0.0f;
        z[r] += e;
        zk[r] += e * kpv;
      }
    }
  }
#pragma unroll
  for (int r = 0; r < 4; r++) {
#pragma unroll
    for (int m = 1; m < 16; m <<= 1) {
      z[r] += __shfl_xor(z[r], m);
      zk[r] += __shfl_xor(zk[r], m);
    }
  }
  float inv[4];
#pragma unroll
  for (int r = 0; r < 4; r++) inv[r] = 1.0f / (zk[r] + EPS_ * z[r]);

  f32x4 cacc[8];
#pragma unroll
  for (int n = 0; n < 8; n++) cacc[n] = zero4();

  // ---- pass 2: normalized attn write + PV ----
  for (int st = 0; st < 32; st++) {
    int s0 = st * 64;
    if (s0 > qbase + 63) { // strictly above diagonal: zero-fill
      float4 zf; zf.x = 0.f; zf.y = 0.f; zf.z = 0.f; zf.w = 0.f;
#pragma unroll
      for (int it = 0; it < 4; it++) {
        int row = (tid >> 4) + it * 16;
        *(float4*)(ap + (size_t)row * 2048 + s0 + (tid & 15) * 4) = zf;
      }
      continue;
    }
    __syncthreads();
#pragma unroll
    for (int it = 0; it < 4; it++) {
      gl_lds16(kp + (size_t)(s0 + srow + it * 16) * 512 + scol, (void*)(Ks + tid * 8 + it * 2048));
      gl_lds16(vp + (size_t)(vrow + it * 32) * 4096 + s0 + vcol, (void*)(Vs + tid * 8 + it * 2048));
    }
    __syncthreads();
#pragma unroll
    for (int j = 0; j < 4; j++) {
      f32x4 sc = zero4();
#pragma unroll
      for (int ks = 0; ks < 4; ks++) {
        bf16x8 kf = *(const bf16x8*)(Ks + (j * 16 + lr) * 128 + ks * 32 + g * 8);
        sc = __builtin_amdgcn_mfma_f32_16x16x32_bf16(qa[ks], kf, sc, 0, 0, 0);
      }
      int sg = s0 + j * 16 + lr;
      float kpv = keeps[sg];
#pragma unroll
      for (int r = 0; r < 4; r++) {
        int row = wid * 16 + g * 4 + r;
        int tg = qbase + row;
        float e = (sg <= tg) ? __builtin_amdgcn_exp2f(sc[r] * SCL) : 0.0f;
        float a = e * kpv * inv[r];
        ap[(size_t)row * 2048 + sg] = a;
        Ps[wid][(g * 4 + r) * 64 + j * 16 + lr] = f2bf(a);
      }
    }
    asm volatile("s_waitcnt lgkmcnt(0)" ::: "memory");
    __builtin_amdgcn_sched_barrier(0);
#pragma unroll
    for (int kk = 0; kk < 2; kk++) {
      bf16x8 pa = *(const bf16x8*)(&Ps[wid][lr * 64 + kk * 32 + g * 8]);
#pragma unroll
      for (int n = 0; n < 8; n++) {
        bf16x8 vf = *(const bf16x8*)(Vs + (n * 16 + lr) * 64 + kk * 32 + g * 8);
        cacc[n] = __builtin_amdgcn_mfma_f32_16x16x32_bf16(pa, vf, cacc[n], 0, 0, 0);
      }
    }
  }

#pragma unroll
  for (int n = 0; n < 8; n++)
#pragma unroll
    for (int r = 0; r < 4; r++)
      cp[(size_t)(wid * 16 + g * 4 + r) * 2048 + n * 16 + lr] = f2bf(cacc[n][r]);
}

extern "C" void kernel_launch(void* const* d_in, const int* in_sizes, int n_in,
                              void* d_out, int out_size, void* d_ws, size_t ws_size,
                              hipStream_t stream) {
  const float* hs = (const float*)d_in[0];
  const float* Wq = (const float*)d_in[1];
  const float* Wk = (const float*)d_in[2];
  const float* Wv = (const float*)d_in[3];
  const float* Wo = (const float*)d_in[4];
  const int* mask = (const int*)d_in[5];

  char* w = (char*)d_ws;
  unsigned short* hsb = (unsigned short*)w; w += (size_t)M_ * C_ * 2;        // 16 MB
  unsigned short* Wqt = (unsigned short*)w; w += (size_t)2048 * 2048 * 2;    // 8 MB
  unsigned short* Wkt = (unsigned short*)w; w += (size_t)512 * 2048 * 2;     // 2 MB
  unsigned short* Wvt = (unsigned short*)w; w += (size_t)512 * 2048 * 2;     // 2 MB
  unsigned short* Wot = (unsigned short*)w; w += (size_t)2048 * 2048 * 2;    // 8 MB
  unsigned short* qbuf = (unsigned short*)w; w += (size_t)M_ * 2048 * 2;     // 16 MB
  unsigned short* kbuf = (unsigned short*)w; w += (size_t)M_ * 512 * 2;      // 4 MB
  unsigned short* vtb = (unsigned short*)w; w += (size_t)512 * M_ * 2;       // 4 MB
  unsigned short* ctxb = (unsigned short*)w; w += (size_t)M_ * 2048 * 2;     // 16 MB

  float* out = (float*)d_out;
  float* attn = out + (size_t)M_ * C_;

  // convert / transpose weights + activations to bf16
  k_cvt<<<2048, 256, 0, stream>>>(hs, hsb, M_ * C_);
  k_cvt_t<<<dim3(2048 / 32, 2048 / 32), dim3(32, 8), 0, stream>>>(Wq, Wqt, 2048, 2048);
  k_cvt_t<<<dim3(512 / 32, 2048 / 32), dim3(32, 8), 0, stream>>>(Wk, Wkt, 2048, 512);
  k_cvt_t<<<dim3(512 / 32, 2048 / 32), dim3(32, 8), 0, stream>>>(Wv, Wvt, 2048, 512);
  k_cvt_t<<<dim3(2048 / 32, 2048 / 32), dim3(32, 8), 0, stream>>>(Wo, Wot, 2048, 2048);

  // projections: q [4096,2048], k [4096,512], v^T [512,4096] (via swapped operands)
  k_gemm<0><<<dim3(2048 / 128, 4096 / 128), 256, 0, stream>>>(hsb, Wqt, qbuf, 4096, 2048, 2048);
  k_gemm<0><<<dim3(512 / 128, 4096 / 128), 256, 0, stream>>>(hsb, Wkt, kbuf, 4096, 512, 2048);
  k_gemm<0><<<dim3(4096 / 128, 512 / 128), 256, 0, stream>>>(Wvt, hsb, vtb, 512, 4096, 2048);

  // fused attention: attn_w (f32, pruned+renormalized) + ctx (bf16)
  k_attn<<<dim3(32, 32), 256, 0, stream>>>(qbuf, kbuf, vtb, mask, attn, ctxb);

  // output projection (f32 out)
  k_gemm<1><<<dim3(2048 / 128, 4096 / 128), 256, 0, stream>>>(ctxb, Wot, out, 4096, 2048, 2048);
}

// Round 2
// 429.270 us; speedup vs baseline: 1.4315x; 1.4315x over previous
//
#include <hip/hip_runtime.h>
#include <hip/hip_bf16.h>
#include <stdint.h>

#define B_ 2
#define T_ 2048
#define C_ 2048
#define H_ 16
#define HKV_ 4
#define D_ 128
#define M_ (B_*T_)          // 4096 rows of hidden_states
// scale * log2(e): exp(x*scale) == exp2(x * SCL)
static constexpr float SCL = 0.08838834764831845f * 1.4426950408889634f;
static constexpr float EPS_ = 1e-6f;

typedef short bf16x8 __attribute__((ext_vector_type(8)));
typedef float f32x4 __attribute__((ext_vector_type(4)));

__device__ __forceinline__ f32x4 zero4() {
  f32x4 v; v[0] = 0.f; v[1] = 0.f; v[2] = 0.f; v[3] = 0.f; return v;
}

__device__ __forceinline__ unsigned short f2bf(float x) {
  union { float f; unsigned u; } v; v.f = x;
  unsigned r = (v.u + 0x7FFFu + ((v.u >> 16) & 1u)) >> 16;
  return (unsigned short)r;
}

__device__ __forceinline__ void gl_lds16(const void* g, void* l) {
  __builtin_amdgcn_global_load_lds((const __attribute__((address_space(1))) void*)g,
                                   (__attribute__((address_space(3))) void*)l, 16, 0, 0);
}

// ---------------- f32 -> bf16 elementwise convert ----------------
__global__ void k_cvt(const float* __restrict__ in, unsigned short* __restrict__ out, int n) {
  int i = (blockIdx.x * blockDim.x + threadIdx.x) * 8;
  int stride = gridDim.x * blockDim.x * 8;
  for (; i < n; i += stride) {
    float4 a = *(const float4*)(in + i);
    float4 b = *(const float4*)(in + i + 4);
    ushort4 o0; o0.x = f2bf(a.x); o0.y = f2bf(a.y); o0.z = f2bf(a.z); o0.w = f2bf(a.w);
    ushort4 o1; o1.x = f2bf(b.x); o1.y = f2bf(b.y); o1.z = f2bf(b.z); o1.w = f2bf(b.w);
    *(ushort4*)(out + i) = o0;
    *(ushort4*)(out + i + 4) = o1;
  }
}

// ------------- f32 -> bf16 transpose convert: out[c][r] = in[r][c] -------------
__global__ void k_cvt_t(const float* __restrict__ in, unsigned short* __restrict__ out,
                        int R, int Cc) {
  __shared__ float ld[32][33];
  int c0 = blockIdx.x * 32, r0 = blockIdx.y * 32;
  int x = threadIdx.x, y = threadIdx.y; // 32 x 8
#pragma unroll
  for (int i = 0; i < 4; i++)
    ld[y * 4 + i][x] = in[(size_t)(r0 + y * 4 + i) * Cc + c0 + x];
  __syncthreads();
#pragma unroll
  for (int i = 0; i < 4; i++)
    out[(size_t)(c0 + y * 4 + i) * R + r0 + x] = f2bf(ld[x][y * 4 + i]);
}

// ---------------- bf16 GEMM: C[M][N] = A[M][K] * Bt[N][K]^T ----------------
// BM=BN=128, BK=64, 256 threads (4 waves, 2x2), wave tile 64x64 (4x4 of 16x16)
template <int WRITE_F32>
__global__ __launch_bounds__(256) void k_gemm(const unsigned short* __restrict__ A,
                                              const unsigned short* __restrict__ Bt,
                                              void* __restrict__ Cout,
                                              int Mdim, int Ndim, int K) {
  __shared__ __align__(16) unsigned short As[128 * 64];
  __shared__ __align__(16) unsigned short Bs[128 * 64];
  const int tid = threadIdx.x;
  const int wid = tid >> 6, lane = tid & 63;
  const int wm = wid >> 1, wn = wid & 1;
  const int m0 = blockIdx.y * 128, n0 = blockIdx.x * 128;
  const int lrow = tid >> 3, lcol = (tid & 7) * 8;
  const int g = lane >> 4, lr = lane & 15;

  f32x4 acc[4][4];
#pragma unroll
  for (int i = 0; i < 4; i++)
#pragma unroll
    for (int j = 0; j < 4; j++) acc[i][j] = zero4();

  for (int k0 = 0; k0 < K; k0 += 64) {
    __syncthreads();
#pragma unroll
    for (int it = 0; it < 4; it++) {
      gl_lds16(A + (size_t)(m0 + lrow + it * 32) * K + k0 + lcol, (void*)(As + tid * 8 + it * 2048));
      gl_lds16(Bt + (size_t)(n0 + lrow + it * 32) * K + k0 + lcol, (void*)(Bs + tid * 8 + it * 2048));
    }
    __syncthreads();
#pragma unroll
    for (int kk = 0; kk < 2; kk++) {
      bf16x8 af[4], bfr[4];
#pragma unroll
      for (int i = 0; i < 4; i++)
        af[i] = *(const bf16x8*)(As + (wm * 64 + i * 16 + lr) * 64 + kk * 32 + g * 8);
#pragma unroll
      for (int j = 0; j < 4; j++)
        bfr[j] = *(const bf16x8*)(Bs + (wn * 64 + j * 16 + lr) * 64 + kk * 32 + g * 8);
#pragma unroll
      for (int i = 0; i < 4; i++)
#pragma unroll
        for (int j = 0; j < 4; j++)
          acc[i][j] = __builtin_amdgcn_mfma_f32_16x16x32_bf16(af[i], bfr[j], acc[i][j], 0, 0, 0);
    }
  }

#pragma unroll
  for (int i = 0; i < 4; i++)
#pragma unroll
    for (int j = 0; j < 4; j++)
#pragma unroll
      for (int r = 0; r < 4; r++) {
        int row = m0 + wm * 64 + i * 16 + g * 4 + r;
        int col = n0 + wn * 64 + j * 16 + lr;
        if (WRITE_F32)
          ((float*)Cout)[(size_t)row * Ndim + col] = acc[i][j][r];
        else
          ((unsigned short*)Cout)[(size_t)row * Ndim + col] = f2bf(acc[i][j][r]);
      }
}

// ---------------- fused causal GQA attention with prune+renorm ----------------
// grid (32 b*h, 32 qtiles[reversed]), 256 threads = 4 waves
// LDS tiles XOR-swizzled (T2): physical_byte_in_row = logical ^ ((row&7)<<4).
// global_load_lds dest stays linear; global SOURCE is pre-swizzled per-lane (m173).
__global__ __launch_bounds__(256) void k_attn(const unsigned short* __restrict__ qb,  // [4096][2048]
                                              const unsigned short* __restrict__ kb,  // [4096][512]
                                              const unsigned short* __restrict__ vt,  // [512][4096]
                                              const int* __restrict__ mask,           // [2048]
                                              float* __restrict__ attn,               // [B,H,T,S]
                                              unsigned short* __restrict__ ctx)       // [4096][2048]
{
  __shared__ __align__(16) unsigned short Ks[64 * 128];
  __shared__ __align__(16) unsigned short Vs[128 * 64];
  __shared__ __align__(16) unsigned short Ps[4][16 * 64];
  __shared__ float keeps[2048];

  const int tid = threadIdx.x;
  const int wid = tid >> 6, lane = tid & 63;
  const int g = lane >> 4, lr = lane & 15;
  const int lr7 = lr & 7;
  const int qt = 31 - blockIdx.y;     // heavy tiles dispatched first (LPT)
  const int bh = blockIdx.x;
  const int b = bh >> 4, h = bh & 15, hkv = h >> 2;
  const int qbase = qt * 64;

  const unsigned short* qp = qb + (size_t)(b * T_ + qbase) * 2048 + h * 128;
  const unsigned short* kp = kb + (size_t)(b * T_) * 512 + hkv * 128;
  const unsigned short* vp = vt + (size_t)(hkv * 128) * 4096 + b * T_;
  float* ap = attn + (size_t)(bh * T_ + qbase) * 2048;
  unsigned short* cp = ctx + (size_t)(b * T_ + qbase) * 2048 + h * 128;

#pragma unroll
  for (int i = 0; i < 8; i++)
    keeps[tid * 8 + i] = (mask[tid * 8 + i] != 0) ? 1.0f : 0.0f;

  // Q fragments (held in registers for both passes)
  bf16x8 qa[4];
#pragma unroll
  for (int ks = 0; ks < 4; ks++)
    qa[ks] = *(const bf16x8*)(qp + (size_t)(wid * 16 + lr) * 2048 + ks * 32 + g * 8);

  const int ntile = qt + 1;
  float z[4] = {0, 0, 0, 0}, zk[4] = {0, 0, 0, 0};

  // staging geometry with swizzled global source columns
  const int srow = tid >> 4;                                       // K: 16 thr/row (256B)
  const int scolb = ((tid & 15) * 16) ^ ((srow & 7) << 4);         // swizzled byte col
  const int vrow = tid >> 3;                                       // V: 8 thr/row (128B)
  const int vcolb = ((tid & 7) * 16) ^ ((vrow & 7) << 4);

  // ---- pass 1: row sums Z (all causal) and S_keep (kept causal) ----
  for (int st = 0; st < ntile; st++) {
    int s0 = st * 64;
    __syncthreads();
#pragma unroll
    for (int it = 0; it < 4; it++)
      gl_lds16(kp + (size_t)(s0 + srow + it * 16) * 512 + (scolb >> 1),
               (void*)(Ks + tid * 8 + it * 2048));
    __syncthreads();
#pragma unroll
    for (int j = 0; j < 4; j++) {
      f32x4 sc = zero4();
      const unsigned short* kbase = Ks + (j * 16 + lr) * 128;
#pragma unroll
      for (int ks = 0; ks < 4; ks++) {
        bf16x8 kf = *(const bf16x8*)(kbase + (((ks * 64 + g * 16) ^ (lr7 << 4)) >> 1));
        sc = __builtin_amdgcn_mfma_f32_16x16x32_bf16(qa[ks], kf, sc, 0, 0, 0);
      }
      int sg = s0 + j * 16 + lr;
      float kpv = keeps[sg];
#pragma unroll
      for (int r = 0; r < 4; r++) {
        int tg = qbase + wid * 16 + g * 4 + r;
        float e = (sg <= tg) ? __builtin_amdgcn_exp2f(sc[r] * SCL) : 0.0f;
        z[r] += e;
        zk[r] += e * kpv;
      }
    }
  }
#pragma unroll
  for (int r = 0; r < 4; r++) {
#pragma unroll
    for (int m = 1; m < 16; m <<= 1) {
      z[r] += __shfl_xor(z[r], m);
      zk[r] += __shfl_xor(zk[r], m);
    }
  }
  float inv[4];
#pragma unroll
  for (int r = 0; r < 4; r++) inv[r] = 1.0f / (zk[r] + EPS_ * z[r]);

  f32x4 cacc[8];
#pragma unroll
  for (int n = 0; n < 8; n++) cacc[n] = zero4();

  // ---- pass 2: normalized attn write + PV ----
  for (int st = 0; st < 32; st++) {
    int s0 = st * 64;
    if (s0 > qbase + 63) { // strictly above diagonal: zero-fill
      float4 zf; zf.x = 0.f; zf.y = 0.f; zf.z = 0.f; zf.w = 0.f;
#pragma unroll
      for (int it = 0; it < 4; it++) {
        int row = (tid >> 4) + it * 16;
        *(float4*)(ap + (size_t)row * 2048 + s0 + (tid & 15) * 4) = zf;
      }
      continue;
    }
    __syncthreads();
#pragma unroll
    for (int it = 0; it < 4; it++) {
      gl_lds16(kp + (size_t)(s0 + srow + it * 16) * 512 + (scolb >> 1),
               (void*)(Ks + tid * 8 + it * 2048));
      gl_lds16(vp + (size_t)(vrow + it * 32) * 4096 + s0 + (vcolb >> 1),
               (void*)(Vs + tid * 8 + it * 2048));
    }
    __syncthreads();
#pragma unroll
    for (int j = 0; j < 4; j++) {
      f32x4 sc = zero4();
      const unsigned short* kbase = Ks + (j * 16 + lr) * 128;
#pragma unroll
      for (int ks = 0; ks < 4; ks++) {
        bf16x8 kf = *(const bf16x8*)(kbase + (((ks * 64 + g * 16) ^ (lr7 << 4)) >> 1));
        sc = __builtin_amdgcn_mfma_f32_16x16x32_bf16(qa[ks], kf, sc, 0, 0, 0);
      }
      int sg = s0 + j * 16 + lr;
      float kpv = keeps[sg];
#pragma unroll
      for (int r = 0; r < 4; r++) {
        int row = wid * 16 + g * 4 + r;
        int tg = qbase + row;
        float e = (sg <= tg) ? __builtin_amdgcn_exp2f(sc[r] * SCL) : 0.0f;
        float a = e * kpv * inv[r];
        ap[(size_t)row * 2048 + sg] = a;
        int prow = g * 4 + r;
        Ps[wid][prow * 64 + (((j * 32 + lr * 2) ^ ((prow & 7) << 4)) >> 1)] = f2bf(a);
      }
    }
    asm volatile("s_waitcnt lgkmcnt(0)" ::: "memory");
    __builtin_amdgcn_sched_barrier(0);
#pragma unroll
    for (int kk = 0; kk < 2; kk++) {
      bf16x8 pa = *(const bf16x8*)(&Ps[wid][lr * 64 + (((kk * 64 + g * 16) ^ (lr7 << 4)) >> 1)]);
#pragma unroll
      for (int n = 0; n < 8; n++) {
        bf16x8 vf = *(const bf16x8*)(Vs + (n * 16 + lr) * 64 + (((kk * 64 + g * 16) ^ (lr7 << 4)) >> 1));
        cacc[n] = __builtin_amdgcn_mfma_f32_16x16x32_bf16(pa, vf, cacc[n], 0, 0, 0);
      }
    }
  }

#pragma unroll
  for (int n = 0; n < 8; n++)
#pragma unroll
    for (int r = 0; r < 4; r++)
      cp[(size_t)(wid * 16 + g * 4 + r) * 2048 + n * 16 + lr] = f2bf(cacc[n][r]);
}

extern "C" void kernel_launch(void* const* d_in, const int* in_sizes, int n_in,
                              void* d_out, int out_size, void* d_ws, size_t ws_size,
                              hipStream_t stream) {
  const float* hs = (const float*)d_in[0];
  const float* Wq = (const float*)d_in[1];
  const float* Wk = (const float*)d_in[2];
  const float* Wv = (const float*)d_in[3];
  const float* Wo = (const float*)d_in[4];
  const int* mask = (const int*)d_in[5];

  char* w = (char*)d_ws;
  unsigned short* hsb = (unsigned short*)w; w += (size_t)M_ * C_ * 2;        // 16 MB
  unsigned short* Wqt = (unsigned short*)w; w += (size_t)2048 * 2048 * 2;    // 8 MB
  unsigned short* Wkt = (unsigned short*)w; w += (size_t)512 * 2048 * 2;     // 2 MB
  unsigned short* Wvt = (unsigned short*)w; w += (size_t)512 * 2048 * 2;     // 2 MB
  unsigned short* Wot = (unsigned short*)w; w += (size_t)2048 * 2048 * 2;    // 8 MB
  unsigned short* qbuf = (unsigned short*)w; w += (size_t)M_ * 2048 * 2;     // 16 MB
  unsigned short* kbuf = (unsigned short*)w; w += (size_t)M_ * 512 * 2;      // 4 MB
  unsigned short* vtb = (unsigned short*)w; w += (size_t)512 * M_ * 2;       // 4 MB
  unsigned short* ctxb = (unsigned short*)w; w += (size_t)M_ * 2048 * 2;     // 16 MB

  float* out = (float*)d_out;
  float* attn = out + (size_t)M_ * C_;

  // convert / transpose weights + activations to bf16
  k_cvt<<<2048, 256, 0, stream>>>(hs, hsb, M_ * C_);
  k_cvt_t<<<dim3(2048 / 32, 2048 / 32), dim3(32, 8), 0, stream>>>(Wq, Wqt, 2048, 2048);
  k_cvt_t<<<dim3(512 / 32, 2048 / 32), dim3(32, 8), 0, stream>>>(Wk, Wkt, 2048, 512);
  k_cvt_t<<<dim3(512 / 32, 2048 / 32), dim3(32, 8), 0, stream>>>(Wv, Wvt, 2048, 512);
  k_cvt_t<<<dim3(2048 / 32, 2048 / 32), dim3(32, 8), 0, stream>>>(Wo, Wot, 2048, 2048);

  // projections: q [4096,2048], k [4096,512], v^T [512,4096] (via swapped operands)
  k_gemm<0><<<dim3(2048 / 128, 4096 / 128), 256, 0, stream>>>(hsb, Wqt, qbuf, 4096, 2048, 2048);
  k_gemm<0><<<dim3(512 / 128, 4096 / 128), 256, 0, stream>>>(hsb, Wkt, kbuf, 4096, 512, 2048);
  k_gemm<0><<<dim3(4096 / 128, 512 / 128), 256, 0, stream>>>(Wvt, hsb, vtb, 512, 4096, 2048);

  // fused attention: attn_w (f32, pruned+renormalized) + ctx (bf16)
  k_attn<<<dim3(32, 32), 256, 0, stream>>>(qbuf, kbuf, vtb, mask, attn, ctxb);

  // output projection (f32 out)
  k_gemm<1><<<dim3(2048 / 128, 4096 / 128), 256, 0, stream>>>(ctxb, Wot, out, 4096, 2048, 2048);
}